// Round 6
// baseline (33.863 us; speedup 1.0000x reference)
//
#include <hip/hip_runtime.h>
#include <math.h>

#define BATCH 128
#define NPRE  1024
#define NPOST 256
#define NCH   16     // k-chunks per neuron (1 wave per chunk)
#define CLEN  64     // NPRE / NCH
#define NJ    64     // neurons per scan block (NPOST/4)
#define CH    8      // weight prefetch batch
#define TABSTR 1040  // float4 stride per batch row (1025 used)

__device__ __forceinline__ float rlf(float v, int lane) {
    // wave-uniform lane -> v_readlane_b32 (no LDS traffic)
    return __int_as_float(__builtin_amdgcn_readlane(__float_as_int(v), lane));
}

__device__ __forceinline__ float lambertw0_f(float z) {
    // Principal branch for z in [-1/e, 0); mirrors reference (clip + init + 12 Halley)
    const float INV_E = 0.36787944117144233f;
    float zc = fminf(fmaxf(z, -INV_E + 1e-8f), -1e-30f);
    float w;
    if (zc < -0.2f) {
        w = -1.0f + sqrtf(2.0f * (1.0f + 2.718281828459045f * zc));
    } else {
        w = zc * (1.0f - zc);
    }
#pragma unroll
    for (int it = 0; it < 12; ++it) {
        float ew  = expf(w);
        float f   = w * ew - zc;
        float wp1 = w + 1.0f;
        w = w - f / (ew * wp1 - (w + 2.0f) * f / (2.0f * wp1));
    }
    return w;
}

__device__ __forceinline__ unsigned long long shflxor64(unsigned long long v, int s) {
    unsigned lo = (unsigned)v, hi = (unsigned)(v >> 32);
    lo = __shfl_xor(lo, s);
    hi = __shfl_xor(hi, s);
    return (((unsigned long long)hi) << 32) | lo;
}

// ---------------- kernel 1: per-row stable argsort + exp tables ----------------
__global__ __launch_bounds__(1024)
void ttfs_sort(const float* __restrict__ spikes,
               float4* __restrict__ gtab, int* __restrict__ gsidx)
{
    __shared__ unsigned long long sbuf[2][NPRE];
    const int tid = threadIdx.x;
    const int b   = blockIdx.x;

    float s = spikes[b * NPRE + tid];
    unsigned long long v =
        (((unsigned long long)__float_as_uint(s)) << 32) | (unsigned)tid;

    int p = 0;
    for (int size = 2; size <= NPRE; size <<= 1) {
        int stride = size >> 1;
        for (; stride >= 64; stride >>= 1) {
            sbuf[p][tid] = v;
            __syncthreads();
            unsigned long long q = sbuf[p][tid ^ stride];
            p ^= 1;   // next LDS phase writes the other buffer: single barrier/phase
            bool keepmin = (((tid & stride) == 0) == ((tid & size) == 0));
            v = ((q < v) == keepmin) ? q : v;
        }
        for (stride = (stride > 32 ? 32 : stride); stride >= 1; stride >>= 1) {
            unsigned long long q = shflxor64(v, stride);
            bool keepmin = (((tid & stride) == 0) == ((tid & size) == 0));
            v = ((q < v) == keepmin) ? q : v;
        }
    }

    float sv = __uint_as_float((unsigned)(v >> 32));
    float e  = expf(sv);
    gtab[b * TABSTR + tid]  = make_float4(sv, e, sv * e, 0.0f);
    gsidx[b * NPRE + tid]   = (int)(unsigned)(v & 0xffffffffULL);
    if (tid == 0)
        gtab[b * TABSTR + NPRE] = make_float4(INFINITY, INFINITY, 0.0f, 0.0f);
}

// ---------------- kernel 2: chunked prefix scan + first-crossing ----------------
__global__ __launch_bounds__(1024, 8)
void ttfs_scan(const float4* __restrict__ gtab, const int* __restrict__ gsidx,
               const float* __restrict__ Wt, float* __restrict__ out)
{
    __shared__ int    sidx[NPRE + 4];
    __shared__ float  cA[NCH][NJ], cB[NCH][NJ];
    __shared__ int    ffk[NCH][NJ];
    __shared__ float  ffA[NCH][NJ], ffB[NCH][NJ];

    const int tid = threadIdx.x;
    const int b   = (int)blockIdx.x >> 2;
    const int h   = (int)blockIdx.x & 3;
    const float4* __restrict__ tb = gtab + b * TABSTR;

    sidx[tid] = gsidx[b * NPRE + tid];
    if (tid < 4) sidx[NPRE + tid] = 0;

    const int c  = tid >> 6;         // 0..15 (wave-uniform)
    const int jj = tid & 63;         // lane == neuron
    const int j0 = h * NJ;
    const float* __restrict__ Wcol = Wt + j0 + jj;
    const int k0 = c * CLEN;

    // lane-distributed table: lane L holds entry k0+L == tid
    const float4 tA4  = tb[tid];
    const float4 tEnd = tb[k0 + CLEN];   // chunk boundary (last chunk: +inf pad)
    __syncthreads();                     // sidx staged

    const int4* __restrict__ sidx4 = (const int4*)sidx;

#define LOADW(kb, dst)                                                        \
    {                                                                         \
        _Pragma("unroll")                                                     \
        for (int q = 0; q < CH / 4; ++q) {                                    \
            int4 I = sidx4[(k0 + (kb)) / 4 + q];                              \
            dst[4 * q + 0] = Wcol[I.x * NPOST];                               \
            dst[4 * q + 1] = Wcol[I.y * NPOST];                               \
            dst[4 * q + 2] = Wcol[I.z * NPOST];                               \
            dst[4 * q + 3] = Wcol[I.w * NPOST];                               \
        }                                                                     \
    }

    // pass 1: chunk-local sums (last chunk's sums never used as offsets)
    float A = 0.0f, Bq = 0.0f;
    if (c < NCH - 1) {
        float wv[CH];
        LOADW(0, wv);
        for (int kb = 0; kb < CLEN; kb += CH) {
            float wn[CH];
            const int nb = kb + CH;
            if (nb < CLEN) LOADW(nb, wn);
#pragma unroll
            for (int i = 0; i < CH; ++i) {
                const int Lr = kb + i;
                A  = fmaf(wv[i], rlf(tA4.y, Lr), A);
                Bq = fmaf(wv[i], rlf(tA4.z, Lr), Bq);
            }
            if (nb < CLEN) {
#pragma unroll
                for (int i = 0; i < CH; ++i) wv[i] = wn[i];
            }
        }
    }
    cA[c][jj] = A; cB[c][jj] = Bq;
    __syncthreads();

    // pass 2: exclusive prefix over chunks
    float offA = 0.0f, offB = 0.0f;
    for (int cc = 0; cc < c; ++cc) { offA += cA[cc][jj]; offB += cB[cc][jj]; }

    // pass 3: delayed-gate scan. Gate at iteration kk tests window k0+kk-1:
    //   V(s_{k}) >= 1  <=>  A_{<k}*s_k - B_{<k} >= e^{s_k}
    A = offA; Bq = offB;
    int   fk = -1; float fA = 0.0f, fB = 0.0f;
    bool  done = false;
    if (c > 0) {
        // pre-gate: membrane already crossed before k0 -> earlier chunk owns it.
        // 1e-5 relative margin so cross-chunk ulp reordering can never flip this.
        float s0 = rlf(tA4.x, 0), e0 = rlf(tA4.y, 0);
        done = fmaf(offA, s0, -offB) >= e0 * 1.00001f;
    }
    if (!__all(done)) {
        float wv[CH];
        LOADW(0, wv);
        for (int kb = 0; kb < CLEN; kb += CH) {
            float wn[CH];
            const int nb = kb + CH;
            if (nb < CLEN) LOADW(nb, wn);
#pragma unroll
            for (int i = 0; i < CH; ++i) {
                const int kk = kb + i;
                float sk  = rlf(tA4.x, kk);
                float ek  = rlf(tA4.y, kk);
                float sek = rlf(tA4.z, kk);
                if (!done && kk > 0) {
                    float gate = fmaf(A, sk, -Bq);
                    if (gate >= ek) { fA = A; fB = Bq; fk = k0 + kk - 1; done = true; }
                }
                A  = fmaf(wv[i], ek,  A);
                Bq = fmaf(wv[i], sek, Bq);
            }
            if (__all(done)) break;
            if (nb < CLEN) {
#pragma unroll
                for (int i = 0; i < CH; ++i) wv[i] = wn[i];
            }
        }
        if (!done) {
            // tail gate: window k0+CLEN-1 against chunk boundary (or +inf pad)
            float gate = fmaf(A, tEnd.x, -Bq);
            if (gate >= tEnd.y) { fA = A; fB = Bq; fk = k0 + CLEN - 1; }
        }
    }
    ffk[c][jj] = fk; ffA[c][jj] = fA; ffB[c][jj] = fB;
    __syncthreads();

    // ---- resolve: one thread per neuron picks earliest chunk, Lambert W once ----
    if (tid < NJ) {
        const int jr = tid;
        int fk2 = -1; float fA2 = 0.0f, fB2 = 0.0f;
#pragma unroll
        for (int cc = 0; cc < NCH; ++cc) {
            int k = ffk[cc][jr];
            if (fk2 < 0 && k >= 0) { fk2 = k; fA2 = ffA[cc][jr]; fB2 = ffB[cc][jr]; }
        }
        float result = INFINITY;
        const float INV_E = 0.36787944117144233f;
        const float* __restrict__ Wc2 = Wt + j0 + jr;
        if (fk2 >= 0) {
            float r  = fB2 / fA2;
            float ez = expf(fminf(fmaxf(r, -30.0f), 30.0f));
            float z  = -ez / fA2;
            bool valid = (fA2 > 0.0f) && (z >= -INV_E);
            float t = r - lambertw0_f(z);
            float4 tf  = tb[fk2];
            float4 tf1 = tb[fk2 + 1];      // fk2+1 <= 1024 (+inf pad) ok
            bool ok = valid && (t >= tf.x) && (fk2 == NPRE - 1 || t <= tf1.x);
            if (ok) {
                result = t;
            } else {
                // rare fp-edge fallback: faithful sequential scan from fk2+1
                float A2 = fA2, B2 = fB2;
                for (int k = fk2 + 1; k < NPRE; ++k) {
                    float w = Wc2[sidx[k] * NPOST];
                    float4 t3 = tb[k];
                    A2 = fmaf(w, t3.y, A2);
                    B2 = fmaf(w, t3.z, B2);
                    if (A2 <= 0.0f) continue;
                    float r2  = B2 / A2;
                    float ez2 = expf(fminf(fmaxf(r2, -30.0f), 30.0f));
                    float z2  = -ez2 / A2;
                    if (z2 < -INV_E) continue;
                    float t2 = r2 - lambertw0_f(z2);
                    if (t2 < t3.x) continue;
                    if (k < NPRE - 1 && t2 > tb[k + 1].x) continue;
                    result = t2;
                    break;
                }
            }
        }
        out[b * NPOST + j0 + jr] = result;
    }
}

// ---------------- fallback: proven fused kernel (R4, 28.2us) ----------------
#define FNCH 8
#define FCLEN 128
#define FNJ  128
#define FCH  16

__global__ __launch_bounds__(1024)
void ttfs_fused(const float* __restrict__ spikes,
                const float* __restrict__ Wt,
                float* __restrict__ out)
{
    __shared__ unsigned long long sbuf[2][NPRE];
    __shared__ float4 tab[NPRE + 1];
    __shared__ int    sidx[NPRE + 4];
    __shared__ float  cA[FNCH][FNJ], cB[FNCH][FNJ];
    __shared__ int    ffk[FNCH][FNJ];
    __shared__ float  ffA[FNCH][FNJ], ffB[FNCH][FNJ];

    const int tid = threadIdx.x;
    const int b   = (int)blockIdx.x >> 1;
    const int h   = (int)blockIdx.x & 1;

    {
        float s = spikes[b * NPRE + tid];
        unsigned long long v =
            (((unsigned long long)__float_as_uint(s)) << 32) | (unsigned)tid;
        int p = 0;
        for (int size = 2; size <= NPRE; size <<= 1) {
            int stride = size >> 1;
            for (; stride >= 64; stride >>= 1) {
                sbuf[p][tid] = v;
                __syncthreads();
                unsigned long long q = sbuf[p][tid ^ stride];
                p ^= 1;
                bool keepmin = (((tid & stride) == 0) == ((tid & size) == 0));
                v = ((q < v) == keepmin) ? q : v;
            }
            for (stride = (stride > 32 ? 32 : stride); stride >= 1; stride >>= 1) {
                unsigned long long q = shflxor64(v, stride);
                bool keepmin = (((tid & stride) == 0) == ((tid & size) == 0));
                v = ((q < v) == keepmin) ? q : v;
            }
        }
        float sv = __uint_as_float((unsigned)(v >> 32));
        float e  = expf(sv);
        tab[tid]  = make_float4(sv, e, sv * e, 0.0f);
        sidx[tid] = (int)(unsigned)(v & 0xffffffffULL);
    }
    if (tid == 0) {
        tab[NPRE]  = make_float4(INFINITY, INFINITY, 0.0f, 0.0f);
        sidx[NPRE] = 0; sidx[NPRE + 1] = 0; sidx[NPRE + 2] = 0; sidx[NPRE + 3] = 0;
    }
    __syncthreads();

    const int c  = tid >> 7;
    const int jj = tid & (FNJ - 1);
    const int j0 = h * FNJ;
    const float* __restrict__ Wcol = Wt + j0 + jj;
    const int k0 = c * FCLEN;
    const int4* __restrict__ sidx4 = (const int4*)sidx;

    const int L = tid & 63;
    const float4 tA4  = tab[k0 + L];
    const float4 tB4  = tab[k0 + 64 + L];
    const float4 tEnd = tab[k0 + FCLEN];

#define FLOADW(kb, dst)                                                       \
    {                                                                         \
        _Pragma("unroll")                                                     \
        for (int q = 0; q < FCH / 4; ++q) {                                   \
            int4 I = sidx4[(k0 + (kb)) / 4 + q];                              \
            dst[4 * q + 0] = Wcol[I.x * NPOST];                               \
            dst[4 * q + 1] = Wcol[I.y * NPOST];                               \
            dst[4 * q + 2] = Wcol[I.z * NPOST];                               \
            dst[4 * q + 3] = Wcol[I.w * NPOST];                               \
        }                                                                     \
    }

    float A = 0.0f, Bq = 0.0f;
    if (c < FNCH - 1) {
        float wv[FCH];
        FLOADW(0, wv);
        for (int kb = 0; kb < FCLEN; kb += FCH) {
            float wn[FCH];
            const int nb = kb + FCH;
            if (nb < FCLEN) FLOADW(nb, wn);
            const bool hi   = kb >= 64;
            const float eH  = hi ? tB4.y : tA4.y;
            const float seH = hi ? tB4.z : tA4.z;
#pragma unroll
            for (int i = 0; i < FCH; ++i) {
                const int Lr = (kb + i) & 63;
                A  = fmaf(wv[i], rlf(eH,  Lr), A);
                Bq = fmaf(wv[i], rlf(seH, Lr), Bq);
            }
            if (nb < FCLEN) {
#pragma unroll
                for (int i = 0; i < FCH; ++i) wv[i] = wn[i];
            }
        }
    }
    cA[c][jj] = A; cB[c][jj] = Bq;
    __syncthreads();

    float offA = 0.0f, offB = 0.0f;
    for (int cc = 0; cc < c; ++cc) { offA += cA[cc][jj]; offB += cB[cc][jj]; }

    A = offA; Bq = offB;
    int   fk = -1; float fA = 0.0f, fB = 0.0f;
    bool  done = false;
    if (c > 0) {
        float s0 = rlf(tA4.x, 0), e0 = rlf(tA4.y, 0);
        done = fmaf(offA, s0, -offB) >= e0 * 1.00001f;
    }
    if (!__all(done)) {
        float wv[FCH];
        FLOADW(0, wv);
        for (int kb = 0; kb < FCLEN; kb += FCH) {
            float wn[FCH];
            const int nb = kb + FCH;
            if (nb < FCLEN) FLOADW(nb, wn);
            const bool hi   = kb >= 64;
            const float sH  = hi ? tB4.x : tA4.x;
            const float eH  = hi ? tB4.y : tA4.y;
            const float seH = hi ? tB4.z : tA4.z;
#pragma unroll
            for (int i = 0; i < FCH; ++i) {
                const int kk = kb + i;
                const int Lr = kk & 63;
                float sk  = rlf(sH,  Lr);
                float ek  = rlf(eH,  Lr);
                float sek = rlf(seH, Lr);
                if (!done && kk > 0) {
                    float gate = fmaf(A, sk, -Bq);
                    if (gate >= ek) { fA = A; fB = Bq; fk = k0 + kk - 1; done = true; }
                }
                A  = fmaf(wv[i], ek,  A);
                Bq = fmaf(wv[i], sek, Bq);
            }
            if (__all(done)) break;
            if (nb < FCLEN) {
#pragma unroll
                for (int i = 0; i < FCH; ++i) wv[i] = wn[i];
            }
        }
        if (!done) {
            float gate = fmaf(A, tEnd.x, -Bq);
            if (gate >= tEnd.y) { fA = A; fB = Bq; fk = k0 + FCLEN - 1; }
        }
    }
    ffk[c][jj] = fk; ffA[c][jj] = fA; ffB[c][jj] = fB;
    __syncthreads();

    if (tid < FNJ) {
        const int jr = tid;
        int fk2 = -1; float fA2 = 0.0f, fB2 = 0.0f;
#pragma unroll
        for (int cc = 0; cc < FNCH; ++cc) {
            int k = ffk[cc][jr];
            if (fk2 < 0 && k >= 0) { fk2 = k; fA2 = ffA[cc][jr]; fB2 = ffB[cc][jr]; }
        }
        float result = INFINITY;
        const float INV_E = 0.36787944117144233f;
        const float* __restrict__ Wc2 = Wt + j0 + jr;
        if (fk2 >= 0) {
            float r  = fB2 / fA2;
            float ez = expf(fminf(fmaxf(r, -30.0f), 30.0f));
            float z  = -ez / fA2;
            bool valid = (fA2 > 0.0f) && (z >= -INV_E);
            float t = r - lambertw0_f(z);
            bool ok = valid && (t >= tab[fk2].x) && (fk2 == NPRE - 1 || t <= tab[fk2 + 1].x);
            if (ok) {
                result = t;
            } else {
                float A2 = fA2, B2 = fB2;
                for (int k = fk2 + 1; k < NPRE; ++k) {
                    float w = Wc2[sidx[k] * NPOST];
                    float4 t3 = tab[k];
                    A2 = fmaf(w, t3.y, A2);
                    B2 = fmaf(w, t3.z, B2);
                    if (A2 <= 0.0f) continue;
                    float r2  = B2 / A2;
                    float ez2 = expf(fminf(fmaxf(r2, -30.0f), 30.0f));
                    float z2  = -ez2 / A2;
                    if (z2 < -INV_E) continue;
                    float t2 = r2 - lambertw0_f(z2);
                    if (t2 < t3.x) continue;
                    if (k < NPRE - 1 && t2 > tab[k + 1].x) continue;
                    result = t2;
                    break;
                }
            }
        }
        out[b * NPOST + j0 + jr] = result;
    }
}

extern "C" void kernel_launch(void* const* d_in, const int* in_sizes, int n_in,
                              void* d_out, int out_size, void* d_ws, size_t ws_size,
                              hipStream_t stream) {
    const float* spikes  = (const float*)d_in[0];   // (128, 1024) f32
    const float* weights = (const float*)d_in[1];   // (1024, 256) f32
    float* outp = (float*)d_out;                    // (128, 256) f32

    const size_t tab_bytes  = (size_t)BATCH * TABSTR * sizeof(float4); // 2,129,920
    const size_t sidx_bytes = (size_t)BATCH * NPRE * sizeof(int);      //   524,288
    if (ws_size >= tab_bytes + sidx_bytes) {
        float4* gtab = (float4*)d_ws;
        int*    gsidx = (int*)((char*)d_ws + tab_bytes);
        ttfs_sort<<<dim3(BATCH), dim3(1024), 0, stream>>>(spikes, gtab, gsidx);
        ttfs_scan<<<dim3(BATCH * 4), dim3(1024), 0, stream>>>(gtab, gsidx, weights, outp);
    } else {
        ttfs_fused<<<dim3(BATCH * 2), dim3(1024), 0, stream>>>(spikes, weights, outp);
    }
}

// Round 8
// 28.996 us; speedup vs baseline: 1.1679x; 1.1679x over previous
//
#include <hip/hip_runtime.h>
#include <math.h>

#define BATCH 128
#define NPRE  1024
#define NPOST 256
#define NCH   16     // k-chunks per neuron (1 wave per chunk)
#define CLEN  64     // NPRE / NCH
#define NJ    64     // neurons per block (NPOST/4)
#define CH    4      // weight prefetch batch (one int4 of indices)

__device__ __forceinline__ float rlf(float v, int lane) {
    // wave-uniform lane -> v_readlane_b32 (no LDS traffic)
    return __int_as_float(__builtin_amdgcn_readlane(__float_as_int(v), lane));
}

__device__ __forceinline__ float lambertw0_f(float z) {
    // Principal branch for z in [-1/e, 0); mirrors reference (clip + init + 12 Halley)
    const float INV_E = 0.36787944117144233f;
    float zc = fminf(fmaxf(z, -INV_E + 1e-8f), -1e-30f);
    float w;
    if (zc < -0.2f) {
        w = -1.0f + sqrtf(2.0f * (1.0f + 2.718281828459045f * zc));
    } else {
        w = zc * (1.0f - zc);
    }
#pragma unroll
    for (int it = 0; it < 12; ++it) {
        float ew  = expf(w);
        float f   = w * ew - zc;
        float wp1 = w + 1.0f;
        w = w - f / (ew * wp1 - (w + 2.0f) * f / (2.0f * wp1));
    }
    return w;
}

__global__ __launch_bounds__(1024, 8)
void ttfs_kernel(const float* __restrict__ spikes,   // (BATCH, NPRE)
                 const float* __restrict__ Wt,       // (NPRE, NPOST)
                 float* __restrict__ out)            // (BATCH, NPOST)
{
    // ---- histogram-sort scratch ----
    __shared__ int    cnt[1024];                 // bucket counts
    __shared__ int    bstart[1025];              // bucket exclusive starts
    __shared__ int    wsum[16];                  // per-wave scan totals
    __shared__ unsigned long long tmp64[NPRE];   // provisional (key,idx) scatter
    // ---- scan tables / reduction ----
    __shared__ float4 tab[NPRE + 1];             // (s, e^s, s*e^s, 0) sorted, +inf pad
    __shared__ int    sidx[NPRE + 4];            // sorted original indices
    __shared__ float  cA[NCH][NJ], cB[NCH][NJ];  // chunk sums
    __shared__ int    ffk[NCH][NJ];              // chunk-found k (-1 none)
    __shared__ float  ffA[NCH][NJ], ffB[NCH][NJ];

    const int tid  = threadIdx.x;
    const int lane = tid & 63;
    const int wid  = tid >> 6;
    const int b    = (int)blockIdx.x >> 2;
    const int h    = (int)blockIdx.x & 3;

    // ================= histogram rank-sort (stable by (key asc, idx asc)) ==========
    {
        float s = spikes[b * NPRE + tid];
        unsigned long long v =
            (((unsigned long long)__float_as_uint(s)) << 32) | (unsigned)tid;
        // bucket: uniform [0,1) keys -> ~Poisson(1) occupancy; clamp for safety
        int bucket = (int)(s * 1024.0f);
        bucket = bucket < 0 ? 0 : (bucket > 1023 ? 1023 : bucket);

        cnt[tid] = 0;
        __syncthreads();
        int arr = atomicAdd(&cnt[bucket], 1);   // arrival order within bucket
        __syncthreads();

        // exclusive prefix over 1024 bucket counts: wave shfl-scan + wave totals
        int c0 = cnt[tid];
        int x  = c0;
#pragma unroll
        for (int d = 1; d < 64; d <<= 1) {
            int y = __shfl_up(x, d);
            if (lane >= d) x += y;
        }
        if (lane == 63) wsum[wid] = x;
        __syncthreads();
        int base = 0;
        for (int w = 0; w < wid; ++w) base += wsum[w];
        bstart[tid] = base + x - c0;            // exclusive start of bucket `tid`
        if (tid == 0) bstart[1024] = NPRE;
        __syncthreads();

        int slot = bstart[bucket] + arr;        // provisional (arrival-ordered) slot
        tmp64[slot] = v;
        __syncthreads();

        // exact rank within bucket: count strictly-smaller packed values
        int st = bstart[bucket], en = bstart[bucket + 1];
        int rk = 0;
        for (int q = st; q < en; ++q) rk += (tmp64[q] < v);
        int fin = st + rk;                      // unique: packed values are distinct

        float e = expf(s);
        tab[fin]  = make_float4(s, e, s * e, 0.0f);
        sidx[fin] = tid;
    }
    if (tid == 0) {
        tab[NPRE]  = make_float4(INFINITY, INFINITY, 0.0f, 0.0f);
        sidx[NPRE] = 0; sidx[NPRE + 1] = 0; sidx[NPRE + 2] = 0; sidx[NPRE + 3] = 0;
    }
    __syncthreads();

    // ================= chunked scan: one wave per chunk, 64 neurons ================
    const int c  = wid;              // 0..15 (wave-uniform chunk)
    const int jj = lane;             // lane == neuron
    const int j0 = h * NJ;
    const float* __restrict__ Wcol = Wt + j0 + jj;
    const int k0 = c * CLEN;

    // lane-distributed table: lane L holds entry k0+L == tid
    const float4 tA4  = tab[tid];
    const float4 tEnd = tab[k0 + CLEN];  // chunk boundary (last chunk: +inf pad)

    const int4* __restrict__ sidx4 = (const int4*)sidx;

#define LOADW(kb, dst)                                                        \
    {                                                                         \
        int4 I = sidx4[(k0 + (kb)) >> 2];                                     \
        dst[0] = Wcol[I.x * NPOST];                                           \
        dst[1] = Wcol[I.y * NPOST];                                           \
        dst[2] = Wcol[I.z * NPOST];                                           \
        dst[3] = Wcol[I.w * NPOST];                                           \
    }

    // pass 1: chunk-local sums (last chunk's sums never used as offsets)
    float A = 0.0f, Bq = 0.0f;
    if (c < NCH - 1) {
        float wv[CH];
        LOADW(0, wv);
        for (int kb = 0; kb < CLEN; kb += CH) {
            float wn[CH];
            const int nb = kb + CH;
            if (nb < CLEN) LOADW(nb, wn);
#pragma unroll
            for (int i = 0; i < CH; ++i) {
                const int Lr = kb + i;
                A  = fmaf(wv[i], rlf(tA4.y, Lr), A);
                Bq = fmaf(wv[i], rlf(tA4.z, Lr), Bq);
            }
            if (nb < CLEN) {
#pragma unroll
                for (int i = 0; i < CH; ++i) wv[i] = wn[i];
            }
        }
    }
    cA[c][jj] = A; cB[c][jj] = Bq;
    __syncthreads();

    // pass 2: exclusive prefix over chunks
    float offA = 0.0f, offB = 0.0f;
    for (int cc = 0; cc < c; ++cc) { offA += cA[cc][jj]; offB += cB[cc][jj]; }

    // pass 3: delayed-gate scan. Gate at iteration kk tests window k0+kk-1:
    //   V(s_{k}) >= 1  <=>  A_{<k}*s_k - B_{<k} >= e^{s_k}
    A = offA; Bq = offB;
    int   fk = -1; float fA = 0.0f, fB = 0.0f;
    bool  done = false;
    if (c > 0) {
        // pre-gate: membrane already crossed before k0 -> earlier chunk owns it.
        // 1e-5 relative margin so cross-chunk ulp reordering can never flip this.
        float s0 = rlf(tA4.x, 0), e0 = rlf(tA4.y, 0);
        done = fmaf(offA, s0, -offB) >= e0 * 1.00001f;
    }
    if (!__all(done)) {
        float wv[CH];
        LOADW(0, wv);
        for (int kb = 0; kb < CLEN; kb += CH) {
            float wn[CH];
            const int nb = kb + CH;
            if (nb < CLEN) LOADW(nb, wn);
#pragma unroll
            for (int i = 0; i < CH; ++i) {
                const int kk = kb + i;
                float sk  = rlf(tA4.x, kk);
                float ek  = rlf(tA4.y, kk);
                float sek = rlf(tA4.z, kk);
                if (!done && kk > 0) {
                    float gate = fmaf(A, sk, -Bq);
                    if (gate >= ek) { fA = A; fB = Bq; fk = k0 + kk - 1; done = true; }
                }
                A  = fmaf(wv[i], ek,  A);
                Bq = fmaf(wv[i], sek, Bq);
            }
            if (__all(done)) break;
            if (nb < CLEN) {
#pragma unroll
                for (int i = 0; i < CH; ++i) wv[i] = wn[i];
            }
        }
        if (!done) {
            // tail gate: window k0+CLEN-1 against chunk boundary (or +inf pad)
            float gate = fmaf(A, tEnd.x, -Bq);
            if (gate >= tEnd.y) { fA = A; fB = Bq; fk = k0 + CLEN - 1; }
        }
    }
    ffk[c][jj] = fk; ffA[c][jj] = fA; ffB[c][jj] = fB;
    __syncthreads();

    // ---- resolve: one thread per neuron picks earliest chunk, Lambert W once ----
    if (tid < NJ) {
        const int jr = tid;
        int fk2 = -1; float fA2 = 0.0f, fB2 = 0.0f;
#pragma unroll
        for (int cc = 0; cc < NCH; ++cc) {
            int k = ffk[cc][jr];
            if (fk2 < 0 && k >= 0) { fk2 = k; fA2 = ffA[cc][jr]; fB2 = ffB[cc][jr]; }
        }
        float result = INFINITY;
        const float INV_E = 0.36787944117144233f;
        const float* __restrict__ Wc2 = Wt + j0 + jr;
        if (fk2 >= 0) {
            float r  = fB2 / fA2;
            float ez = expf(fminf(fmaxf(r, -30.0f), 30.0f));
            float z  = -ez / fA2;
            bool valid = (fA2 > 0.0f) && (z >= -INV_E);
            float t = r - lambertw0_f(z);
            bool ok = valid && (t >= tab[fk2].x) && (fk2 == NPRE - 1 || t <= tab[fk2 + 1].x);
            if (ok) {
                result = t;
            } else {
                // rare fp-edge fallback: faithful sequential scan from fk2+1
                float A2 = fA2, B2 = fB2;
                for (int k = fk2 + 1; k < NPRE; ++k) {
                    float w = Wc2[sidx[k] * NPOST];
                    float4 t3 = tab[k];
                    A2 = fmaf(w, t3.y, A2);
                    B2 = fmaf(w, t3.z, B2);
                    if (A2 <= 0.0f) continue;
                    float r2  = B2 / A2;
                    float ez2 = expf(fminf(fmaxf(r2, -30.0f), 30.0f));
                    float z2  = -ez2 / A2;
                    if (z2 < -INV_E) continue;
                    float t2 = r2 - lambertw0_f(z2);
                    if (t2 < t3.x) continue;
                    if (k < NPRE - 1 && t2 > tab[k + 1].x) continue;
                    result = t2;
                    break;
                }
            }
        }
        out[b * NPOST + j0 + jr] = result;
    }
}

extern "C" void kernel_launch(void* const* d_in, const int* in_sizes, int n_in,
                              void* d_out, int out_size, void* d_ws, size_t ws_size,
                              hipStream_t stream) {
    const float* spikes  = (const float*)d_in[0];   // (128, 1024) f32
    const float* weights = (const float*)d_in[1];   // (1024, 256) f32
    float* outp = (float*)d_out;                    // (128, 256) f32
    ttfs_kernel<<<dim3(BATCH * 4), dim3(1024), 0, stream>>>(spikes, weights, outp);
}

// Round 9
// 18.704 us; speedup vs baseline: 1.8105x; 1.5502x over previous
//
#include <hip/hip_runtime.h>
#include <math.h>

#define BATCH 128
#define NPRE  1024
#define NPOST 256
#define NJ    64     // neurons per block (= lanes)
#define NW    16     // waves per block
#define KPW   4      // k's per wave per chunk
#define CLEN  64     // chunk length = NW*KPW
#define NCHK  16     // NPRE / CLEN

__device__ __forceinline__ float lambertw0_f(float z) {
    // Principal branch for z in [-1/e, 0); mirrors reference (clip + init + 12 Halley)
    const float INV_E = 0.36787944117144233f;
    float zc = fminf(fmaxf(z, -INV_E + 1e-8f), -1e-30f);
    float w;
    if (zc < -0.2f) {
        w = -1.0f + sqrtf(2.0f * (1.0f + 2.718281828459045f * zc));
    } else {
        w = zc * (1.0f - zc);
    }
#pragma unroll
    for (int it = 0; it < 12; ++it) {
        float ew  = expf(w);
        float f   = w * ew - zc;
        float wp1 = w + 1.0f;
        w = w - f / (ew * wp1 - (w + 2.0f) * f / (2.0f * wp1));
    }
    return w;
}

__global__ __launch_bounds__(1024, 8)
void ttfs_kernel(const float* __restrict__ spikes,   // (BATCH, NPRE)
                 const float* __restrict__ Wt,       // (NPRE, NPOST)
                 float* __restrict__ out)            // (BATCH, NPOST)
{
    // ---- histogram-sort scratch ----
    __shared__ int    cnt[1024];
    __shared__ int    bstart[1025];
    __shared__ int    wsum[NW];
    __shared__ unsigned long long tmp64[NPRE];
    // ---- tables / chunk partials ----
    __shared__ float4 tab[NPRE + 1];             // (s, e^s, s*e^s, 0) sorted, +inf pad
    __shared__ int    sidx[NPRE + 4];            // sorted original indices
    __shared__ float  pA[NW][NJ + 1], pB[NW][NJ + 1];   // padded: stride 65 kills conflicts
    __shared__ int    allDoneFlag;

    const int tid  = threadIdx.x;
    const int lane = tid & 63;
    const int wid  = tid >> 6;
    const int b    = (int)blockIdx.x >> 2;
    const int h    = (int)blockIdx.x & 3;

    // ================= histogram rank-sort (stable by (key asc, idx asc)) ==========
    {
        float s = spikes[b * NPRE + tid];
        unsigned long long v =
            (((unsigned long long)__float_as_uint(s)) << 32) | (unsigned)tid;
        int bucket = (int)(s * 1024.0f);
        bucket = bucket < 0 ? 0 : (bucket > 1023 ? 1023 : bucket);

        cnt[tid] = 0;
        __syncthreads();
        int arr = atomicAdd(&cnt[bucket], 1);
        __syncthreads();

        int c0 = cnt[tid];
        int x  = c0;
#pragma unroll
        for (int d = 1; d < 64; d <<= 1) {
            int y = __shfl_up(x, d);
            if (lane >= d) x += y;
        }
        if (lane == 63) wsum[wid] = x;
        __syncthreads();
        int base = 0;
        for (int w = 0; w < wid; ++w) base += wsum[w];
        bstart[tid] = base + x - c0;
        if (tid == 0) bstart[1024] = NPRE;
        __syncthreads();

        int slot = bstart[bucket] + arr;
        tmp64[slot] = v;
        __syncthreads();

        int st = bstart[bucket], en = bstart[bucket + 1];
        int rk = 0;
        for (int q = st; q < en; ++q) rk += (tmp64[q] < v);
        int fin = st + rk;

        float e = expf(s);
        tab[fin]  = make_float4(s, e, s * e, 0.0f);
        sidx[fin] = tid;
    }
    if (tid == 0) {
        tab[NPRE]  = make_float4(INFINITY, INFINITY, 0.0f, 0.0f);
        sidx[NPRE] = 0; sidx[NPRE + 1] = 0; sidx[NPRE + 2] = 0; sidx[NPRE + 3] = 0;
    }
    __syncthreads();

    // ================= sequential-chunk scan with block early-exit ================
    const int j0 = h * NJ;
    const float* __restrict__ Wcol = Wt + j0 + lane;   // neuron = lane
    const int4* __restrict__ sidx4 = (const int4*)sidx;
    const int kbase = wid * KPW;                       // wave's k-slice within chunk

    float offA = 0.0f, offB = 0.0f;      // prefix through completed chunks (wave0 lanes)
    float preA = 0.0f, preB = 0.0f;      // prefix before firing chunk
    int   cstar = -1;
    bool  doneJ = false;

    float wv[KPW], wn[KPW];
    {
        int4 I = sidx4[kbase >> 2];
        wv[0] = Wcol[I.x * NPOST]; wv[1] = Wcol[I.y * NPOST];
        wv[2] = Wcol[I.z * NPOST]; wv[3] = Wcol[I.w * NPOST];
    }

    for (int ch = 0; ch < NCHK; ++ch) {
        const int kk0 = ch * CLEN + kbase;
        // prefetch next chunk's weights (in flight across barriers)
        if (ch < NCHK - 1) {
            int4 I = sidx4[(kk0 + CLEN) >> 2];
            wn[0] = Wcol[I.x * NPOST]; wn[1] = Wcol[I.y * NPOST];
            wn[2] = Wcol[I.z * NPOST]; wn[3] = Wcol[I.w * NPOST];
        }
        // wave-local partial sums over its 4 k's (tab reads are wave-uniform broadcasts)
        float a = 0.0f, bq = 0.0f;
#pragma unroll
        for (int i = 0; i < KPW; ++i) {
            float4 t = tab[kk0 + i];
            a  = fmaf(wv[i], t.y, a);
            bq = fmaf(wv[i], t.z, bq);
        }
        pA[wid][lane] = a; pB[wid][lane] = bq;
        __syncthreads();

        if (wid == 0) {
            float ca = 0.0f, cb = 0.0f;
#pragma unroll
            for (int w = 0; w < NW; ++w) { ca += pA[w][lane]; cb += pB[w][lane]; }
            float nA = offA + ca, nB = offB + cb;
            // chunk gate: V(s_next) >= 1  <=>  crossing within windows of chunks <= ch
            float4 tn = tab[(ch + 1) * CLEN];          // ch=15 -> +inf pad
            if (!doneJ) {
                float gate = fmaf(nA, tn.x, -nB);
                if (gate >= tn.y) { cstar = ch; preA = offA; preB = offB; doneJ = true; }
            }
            offA = nA; offB = nB;
            bool all = __all(doneJ);
            if (lane == 0) allDoneFlag = all ? 1 : 0;
        }
        __syncthreads();
        if (allDoneFlag) break;                        // uniform across block
        if (ch < NCHK - 1) {
#pragma unroll
            for (int i = 0; i < KPW; ++i) wv[i] = wn[i];
        }
    }

    // ================= resolve: wave 0, one neuron per lane ========================
    if (wid == 0) {
        float result = INFINITY;
        const float INV_E = 0.36787944117144233f;
        if (doneJ) {
            const int k0 = cstar * CLEN;
            // fine delayed-gate rescan of the firing chunk (sequential, 8-deep prefetch)
            float A = preA, Bq = preB;
            int fk = -1; float fA = 0.0f, fB = 0.0f;
            bool done = false;
            float wl[8], wm[8];
#pragma unroll
            for (int i = 0; i < 8; ++i) wl[i] = Wcol[sidx[k0 + i] * NPOST];
            for (int kb = 0; kb < CLEN; kb += 8) {
                if (kb + 8 < CLEN) {
#pragma unroll
                    for (int i = 0; i < 8; ++i) wm[i] = Wcol[sidx[k0 + kb + 8 + i] * NPOST];
                }
#pragma unroll
                for (int i = 0; i < 8; ++i) {
                    const int kk = kb + i;
                    float4 t = tab[k0 + kk];
                    if (!done && kk > 0) {
                        // window k0+kk-1: V(s_{k0+kk}) >= 1
                        float gate = fmaf(A, t.x, -Bq);
                        if (gate >= t.y) { fA = A; fB = Bq; fk = k0 + kk - 1; done = true; }
                    }
                    A  = fmaf(wl[i], t.y, A);
                    Bq = fmaf(wl[i], t.z, Bq);
                }
                if (kb + 8 < CLEN) {
#pragma unroll
                    for (int i = 0; i < 8; ++i) wl[i] = wm[i];
                }
            }
            if (!done) {
                float4 tn = tab[k0 + CLEN];            // cstar=15 -> +inf pad
                float gate = fmaf(A, tn.x, -Bq);
                if (gate >= tn.y) { fA = A; fB = Bq; fk = k0 + CLEN - 1; done = true; }
            }

            if (fk >= 0) {
                float r  = fB / fA;
                float ez = expf(fminf(fmaxf(r, -30.0f), 30.0f));
                float z  = -ez / fA;
                bool valid = (fA > 0.0f) && (z >= -INV_E);
                float t = r - lambertw0_f(z);
                bool ok = valid && (t >= tab[fk].x) && (fk == NPRE - 1 || t <= tab[fk + 1].x);
                if (ok) {
                    result = t;
                } else {
                    // rare fp-edge fallback: faithful sequential scan from fk+1
                    float A2 = fA, B2 = fB;
                    for (int k = fk + 1; k < NPRE; ++k) {
                        float w = Wcol[sidx[k] * NPOST];
                        float4 t3 = tab[k];
                        A2 = fmaf(w, t3.y, A2);
                        B2 = fmaf(w, t3.z, B2);
                        if (A2 <= 0.0f) continue;
                        float r2  = B2 / A2;
                        float ez2 = expf(fminf(fmaxf(r2, -30.0f), 30.0f));
                        float z2  = -ez2 / A2;
                        if (z2 < -INV_E) continue;
                        float t2 = r2 - lambertw0_f(z2);
                        if (t2 < t3.x) continue;
                        if (k < NPRE - 1 && t2 > tab[k + 1].x) continue;
                        result = t2;
                        break;
                    }
                }
            } else {
                // ultra-rare tree/sequential mismatch: faithful full scan from 0
                float A2 = 0.0f, B2 = 0.0f;
                for (int k = 0; k < NPRE; ++k) {
                    float w = Wcol[sidx[k] * NPOST];
                    float4 t3 = tab[k];
                    A2 = fmaf(w, t3.y, A2);
                    B2 = fmaf(w, t3.z, B2);
                    if (A2 <= 0.0f) continue;
                    float r2  = B2 / A2;
                    float ez2 = expf(fminf(fmaxf(r2, -30.0f), 30.0f));
                    float z2  = -ez2 / A2;
                    if (z2 < -INV_E) continue;
                    float t2 = r2 - lambertw0_f(z2);
                    if (t2 < t3.x) continue;
                    if (k < NPRE - 1 && t2 > tab[k + 1].x) continue;
                    result = t2;
                    break;
                }
            }
        }
        out[b * NPOST + j0 + lane] = result;
    }
}

extern "C" void kernel_launch(void* const* d_in, const int* in_sizes, int n_in,
                              void* d_out, int out_size, void* d_ws, size_t ws_size,
                              hipStream_t stream) {
    const float* spikes  = (const float*)d_in[0];   // (128, 1024) f32
    const float* weights = (const float*)d_in[1];   // (1024, 256) f32
    float* outp = (float*)d_out;                    // (128, 256) f32
    ttfs_kernel<<<dim3(BATCH * 4), dim3(1024), 0, stream>>>(spikes, weights, outp);
}

// Round 10
// 17.453 us; speedup vs baseline: 1.9403x; 1.0717x over previous
//
#include <hip/hip_runtime.h>
#include <math.h>

#define BATCH 128
#define NPRE  1024
#define NPOST 256
#define NJB   128    // neurons per block (2 per lane)
#define NW    16     // waves per block
#define KPW   4      // k's per wave per chunk
#define CLEN  64     // chunk length = NW*KPW
#define NCHK  16     // NPRE / CLEN

__device__ __forceinline__ float lambertw0_f(float z) {
    // Principal branch for z in [-1/e, 0); mirrors reference (clip + init + 12 Halley)
    const float INV_E = 0.36787944117144233f;
    float zc = fminf(fmaxf(z, -INV_E + 1e-8f), -1e-30f);
    float w;
    if (zc < -0.2f) {
        w = -1.0f + sqrtf(2.0f * (1.0f + 2.718281828459045f * zc));
    } else {
        w = zc * (1.0f - zc);
    }
#pragma unroll
    for (int it = 0; it < 12; ++it) {
        float ew  = expf(w);
        float f   = w * ew - zc;
        float wp1 = w + 1.0f;
        w = w - f / (ew * wp1 - (w + 2.0f) * f / (2.0f * wp1));
    }
    return w;
}

__global__ __launch_bounds__(1024, 4)
void ttfs_kernel(const float* __restrict__ spikes,   // (BATCH, NPRE)
                 const float* __restrict__ Wt,       // (NPRE, NPOST)
                 float* __restrict__ out)            // (BATCH, NPOST)
{
    // ---- histogram-sort scratch ----
    __shared__ int    cnt[1024];
    __shared__ int    bstart[1025];
    __shared__ int    wsum[NW];
    __shared__ unsigned long long tmp64[NPRE];
    // ---- tables / chunk partials ----
    __shared__ float4 tab[NPRE + 1];             // (s, e^s, s*e^s, 0) sorted, +inf pad
    __shared__ int    sidx[NPRE + 4];            // sorted original indices
    __shared__ float  pA[NW][NJB + 2], pB[NW][NJB + 2];
    __shared__ int    flags[2];

    const int tid  = threadIdx.x;
    const int lane = tid & 63;
    const int wid  = tid >> 6;
    const int b    = (int)blockIdx.x >> 1;
    const int h    = (int)blockIdx.x & 1;

    // ================= histogram rank-sort (stable by (key asc, idx asc)) ==========
    {
        float s = spikes[b * NPRE + tid];
        unsigned long long v =
            (((unsigned long long)__float_as_uint(s)) << 32) | (unsigned)tid;
        int bucket = (int)(s * 1024.0f);
        bucket = bucket < 0 ? 0 : (bucket > 1023 ? 1023 : bucket);

        cnt[tid] = 0;
        __syncthreads();
        int arr = atomicAdd(&cnt[bucket], 1);
        __syncthreads();

        int c0 = cnt[tid];
        int x  = c0;
#pragma unroll
        for (int d = 1; d < 64; d <<= 1) {
            int y = __shfl_up(x, d);
            if (lane >= d) x += y;
        }
        if (lane == 63) wsum[wid] = x;
        __syncthreads();
        int base = 0;
        for (int w = 0; w < wid; ++w) base += wsum[w];
        bstart[tid] = base + x - c0;
        if (tid == 0) bstart[1024] = NPRE;
        __syncthreads();

        int slot = bstart[bucket] + arr;
        tmp64[slot] = v;
        __syncthreads();

        int st = bstart[bucket], en = bstart[bucket + 1];
        int rk = 0;
        for (int q = st; q < en; ++q) rk += (tmp64[q] < v);
        int fin = st + rk;

        float e = expf(s);
        tab[fin]  = make_float4(s, e, s * e, 0.0f);
        sidx[fin] = tid;
    }
    if (tid == 0) {
        tab[NPRE]  = make_float4(INFINITY, INFINITY, 0.0f, 0.0f);
        sidx[NPRE] = 0; sidx[NPRE + 1] = 0; sidx[NPRE + 2] = 0; sidx[NPRE + 3] = 0;
    }
    __syncthreads();

    // ================= sequential-chunk scan with block early-exit ================
    const int j0 = h * NJB;
    const float* __restrict__ Wc0 = Wt + j0 + lane;        // neuron = lane
    const float* __restrict__ Wc1 = Wt + j0 + 64 + lane;   // neuron = lane+64
    const int4* __restrict__ sidx4 = (const int4*)sidx;
    const int kbase = wid * KPW;                           // wave's k-slice in chunk

    // reduce-wave state (wave w<2 owns neuron n = w*64+lane)
    float offA = 0.0f, offB = 0.0f;      // prefix through completed chunks
    float preA = 0.0f, preB = 0.0f;      // prefix before firing chunk
    int   cstar = -1;
    bool  doneJ = false;

    float wv[2 * KPW], wn[2 * KPW];
    {
        int4 I = sidx4[kbase >> 2];
        wv[0] = Wc0[I.x * NPOST]; wv[1] = Wc0[I.y * NPOST];
        wv[2] = Wc0[I.z * NPOST]; wv[3] = Wc0[I.w * NPOST];
        wv[4] = Wc1[I.x * NPOST]; wv[5] = Wc1[I.y * NPOST];
        wv[6] = Wc1[I.z * NPOST]; wv[7] = Wc1[I.w * NPOST];
    }

    for (int ch = 0; ch < NCHK; ++ch) {
        const int kk0 = ch * CLEN + kbase;
        // prefetch next chunk's weights (in flight across barriers)
        if (ch < NCHK - 1) {
            int4 I = sidx4[(kk0 + CLEN) >> 2];
            wn[0] = Wc0[I.x * NPOST]; wn[1] = Wc0[I.y * NPOST];
            wn[2] = Wc0[I.z * NPOST]; wn[3] = Wc0[I.w * NPOST];
            wn[4] = Wc1[I.x * NPOST]; wn[5] = Wc1[I.y * NPOST];
            wn[6] = Wc1[I.z * NPOST]; wn[7] = Wc1[I.w * NPOST];
        }
        // wave-local partials over its 4 k's (tab reads are wave-uniform broadcasts)
        float a0 = 0.0f, b0 = 0.0f, a1 = 0.0f, b1 = 0.0f;
#pragma unroll
        for (int i = 0; i < KPW; ++i) {
            float4 t = tab[kk0 + i];
            a0 = fmaf(wv[i],       t.y, a0);
            b0 = fmaf(wv[i],       t.z, b0);
            a1 = fmaf(wv[KPW + i], t.y, a1);
            b1 = fmaf(wv[KPW + i], t.z, b1);
        }
        pA[wid][lane]      = a0; pB[wid][lane]      = b0;
        pA[wid][64 + lane] = a1; pB[wid][64 + lane] = b1;
        __syncthreads();

        if (wid < 2) {
            const int n = (wid << 6) + lane;
            float ca = 0.0f, cb = 0.0f;
#pragma unroll
            for (int w = 0; w < NW; ++w) { ca += pA[w][n]; cb += pB[w][n]; }
            float nA = offA + ca, nB = offB + cb;
            // chunk gate: V(s_next) >= 1  <=>  crossing within windows of chunks <= ch
            float4 tn = tab[(ch + 1) * CLEN];          // ch=15 -> +inf pad
            if (!doneJ) {
                float gate = fmaf(nA, tn.x, -nB);
                if (gate >= tn.y) { cstar = ch; preA = offA; preB = offB; doneJ = true; }
            }
            offA = nA; offB = nB;
            bool all = __all(doneJ);
            if (lane == 0) flags[wid] = all ? 1 : 0;
        }
        __syncthreads();
        if (flags[0] & flags[1]) break;                // uniform across block
        if (ch < NCHK - 1) {
#pragma unroll
            for (int i = 0; i < 2 * KPW; ++i) wv[i] = wn[i];
        }
    }

    // ================= resolve: waves 0-1, one neuron per lane =====================
    if (wid < 2) {
        const int n = (wid << 6) + lane;
        const float* __restrict__ Wcol = Wt + j0 + n;
        float result = INFINITY;
        const float INV_E = 0.36787944117144233f;
        if (doneJ) {
            const int k0 = cstar * CLEN;
            // fine delayed-gate rescan of the firing chunk (sequential, 8-deep prefetch)
            float A = preA, Bq = preB;
            int fk = -1; float fA = 0.0f, fB = 0.0f;
            bool done = false;
            float wl[8], wm[8];
#pragma unroll
            for (int i = 0; i < 8; ++i) wl[i] = Wcol[sidx[k0 + i] * NPOST];
            for (int kb = 0; kb < CLEN; kb += 8) {
                if (kb + 8 < CLEN) {
#pragma unroll
                    for (int i = 0; i < 8; ++i) wm[i] = Wcol[sidx[k0 + kb + 8 + i] * NPOST];
                }
#pragma unroll
                for (int i = 0; i < 8; ++i) {
                    const int kk = kb + i;
                    float4 t = tab[k0 + kk];
                    if (!done && kk > 0) {
                        // window k0+kk-1: V(s_{k0+kk}) >= 1
                        float gate = fmaf(A, t.x, -Bq);
                        if (gate >= t.y) { fA = A; fB = Bq; fk = k0 + kk - 1; done = true; }
                    }
                    A  = fmaf(wl[i], t.y, A);
                    Bq = fmaf(wl[i], t.z, Bq);
                }
                if (kb + 8 < CLEN) {
#pragma unroll
                    for (int i = 0; i < 8; ++i) wl[i] = wm[i];
                }
            }
            if (!done) {
                float4 tn = tab[k0 + CLEN];            // cstar=15 -> +inf pad
                float gate = fmaf(A, tn.x, -Bq);
                if (gate >= tn.y) { fA = A; fB = Bq; fk = k0 + CLEN - 1; done = true; }
            }

            if (fk >= 0) {
                float r  = fB / fA;
                float ez = expf(fminf(fmaxf(r, -30.0f), 30.0f));
                float z  = -ez / fA;
                bool valid = (fA > 0.0f) && (z >= -INV_E);
                float t = r - lambertw0_f(z);
                bool ok = valid && (t >= tab[fk].x) && (fk == NPRE - 1 || t <= tab[fk + 1].x);
                if (ok) {
                    result = t;
                } else {
                    // rare fp-edge fallback: faithful sequential scan from fk+1
                    float A2 = fA, B2 = fB;
                    for (int k = fk + 1; k < NPRE; ++k) {
                        float w = Wcol[sidx[k] * NPOST];
                        float4 t3 = tab[k];
                        A2 = fmaf(w, t3.y, A2);
                        B2 = fmaf(w, t3.z, B2);
                        if (A2 <= 0.0f) continue;
                        float r2  = B2 / A2;
                        float ez2 = expf(fminf(fmaxf(r2, -30.0f), 30.0f));
                        float z2  = -ez2 / A2;
                        if (z2 < -INV_E) continue;
                        float t2 = r2 - lambertw0_f(z2);
                        if (t2 < t3.x) continue;
                        if (k < NPRE - 1 && t2 > tab[k + 1].x) continue;
                        result = t2;
                        break;
                    }
                }
            } else {
                // ultra-rare grouping/sequential mismatch: faithful full scan from 0
                float A2 = 0.0f, B2 = 0.0f;
                for (int k = 0; k < NPRE; ++k) {
                    float w = Wcol[sidx[k] * NPOST];
                    float4 t3 = tab[k];
                    A2 = fmaf(w, t3.y, A2);
                    B2 = fmaf(w, t3.z, B2);
                    if (A2 <= 0.0f) continue;
                    float r2  = B2 / A2;
                    float ez2 = expf(fminf(fmaxf(r2, -30.0f), 30.0f));
                    float z2  = -ez2 / A2;
                    if (z2 < -INV_E) continue;
                    float t2 = r2 - lambertw0_f(z2);
                    if (t2 < t3.x) continue;
                    if (k < NPRE - 1 && t2 > tab[k + 1].x) continue;
                    result = t2;
                    break;
                }
            }
        }
        out[b * NPOST + j0 + n] = result;
    }
}

extern "C" void kernel_launch(void* const* d_in, const int* in_sizes, int n_in,
                              void* d_out, int out_size, void* d_ws, size_t ws_size,
                              hipStream_t stream) {
    const float* spikes  = (const float*)d_in[0];   // (128, 1024) f32
    const float* weights = (const float*)d_in[1];   // (1024, 256) f32
    float* outp = (float*)d_out;                    // (128, 256) f32
    ttfs_kernel<<<dim3(BATCH * 2), dim3(1024), 0, stream>>>(spikes, weights, outp);
}

// Round 11
// 15.211 us; speedup vs baseline: 2.2262x; 1.1473x over previous
//
#include <hip/hip_runtime.h>
#include <math.h>

#define BATCH 128
#define NPRE  1024
#define NPOST 256
#define NJB   128    // neurons per block (2 per lane)
#define NW    16     // waves per block
#define KPW   8      // k's per wave per chunk
#define CLEN  128    // chunk length = NW*KPW
#define NCHK  8      // NPRE / CLEN

__device__ __forceinline__ float lambertw0_f(float z) {
    // Principal branch for z in [-1/e, 0); mirrors reference (clip + init + 12 Halley)
    const float INV_E = 0.36787944117144233f;
    float zc = fminf(fmaxf(z, -INV_E + 1e-8f), -1e-30f);
    float w;
    if (zc < -0.2f) {
        w = -1.0f + sqrtf(2.0f * (1.0f + 2.718281828459045f * zc));
    } else {
        w = zc * (1.0f - zc);
    }
#pragma unroll
    for (int it = 0; it < 12; ++it) {
        float ew  = expf(w);
        float f   = w * ew - zc;
        float wp1 = w + 1.0f;
        w = w - f / (ew * wp1 - (w + 2.0f) * f / (2.0f * wp1));
    }
    return w;
}

__global__ __launch_bounds__(1024, 4)
void ttfs_kernel(const float* __restrict__ spikes,   // (BATCH, NPRE)
                 const float* __restrict__ Wt,       // (NPRE, NPOST)
                 float* __restrict__ out)            // (BATCH, NPOST)
{
    // ---- histogram-sort scratch ----
    __shared__ int    cnt[1024];
    __shared__ int    bstart[1025];
    __shared__ int    wsum[NW];
    __shared__ unsigned long long tmp64[NPRE];
    // ---- tables / chunk partials ----
    __shared__ float4 tab[NPRE + 1];             // (s, e^s, s*e^s, 0) sorted, +inf pad
    __shared__ int    sidx[NPRE + 4];            // sorted original indices
    __shared__ float  pA[NW][NJB + 2], pB[NW][NJB + 2];
    __shared__ int    flags[2];

    const int tid  = threadIdx.x;
    const int lane = tid & 63;
    const int wid  = tid >> 6;
    const int b    = (int)blockIdx.x >> 1;
    const int h    = (int)blockIdx.x & 1;

    // ================= histogram rank-sort (stable by (key asc, idx asc)) ==========
    {
        float s = spikes[b * NPRE + tid];
        unsigned long long v =
            (((unsigned long long)__float_as_uint(s)) << 32) | (unsigned)tid;
        int bucket = (int)(s * 1024.0f);
        bucket = bucket < 0 ? 0 : (bucket > 1023 ? 1023 : bucket);

        cnt[tid] = 0;
        __syncthreads();
        int arr = atomicAdd(&cnt[bucket], 1);
        __syncthreads();

        int c0 = cnt[tid];
        int x  = c0;
#pragma unroll
        for (int d = 1; d < 64; d <<= 1) {
            int y = __shfl_up(x, d);
            if (lane >= d) x += y;
        }
        if (lane == 63) wsum[wid] = x;
        __syncthreads();
        int base = 0;
        for (int w = 0; w < wid; ++w) base += wsum[w];
        bstart[tid] = base + x - c0;
        if (tid == 0) bstart[1024] = NPRE;
        __syncthreads();

        int slot = bstart[bucket] + arr;
        tmp64[slot] = v;
        __syncthreads();

        int st = bstart[bucket], en = bstart[bucket + 1];
        int rk = 0;
        for (int q = st; q < en; ++q) rk += (tmp64[q] < v);
        int fin = st + rk;

        float e = expf(s);
        tab[fin]  = make_float4(s, e, s * e, 0.0f);
        sidx[fin] = tid;
    }
    if (tid == 0) {
        tab[NPRE]  = make_float4(INFINITY, INFINITY, 0.0f, 0.0f);
        sidx[NPRE] = 0; sidx[NPRE + 1] = 0; sidx[NPRE + 2] = 0; sidx[NPRE + 3] = 0;
    }
    __syncthreads();

    // ================= sequential-chunk scan with block early-exit ================
    const int j0 = h * NJB;
    const float* __restrict__ Wc0 = Wt + j0 + lane;        // neuron = lane
    const float* __restrict__ Wc1 = Wt + j0 + 64 + lane;   // neuron = lane+64
    const int4* __restrict__ sidx4 = (const int4*)sidx;
    const int kbase = wid * KPW;                           // wave's k-slice in chunk

    // reduce-wave state (wave w<2 owns neuron n = w*64+lane)
    float offA = 0.0f, offB = 0.0f;      // running prefix (updated per wave-partial)
    float preA = 0.0f, preB = 0.0f;      // prefix before firing 8-k window group
    int   baseK = -1;                    // start of the 8-k group containing firing
    bool  doneJ = false;

#define LOADW2(kstart, dst)                                                   \
    {                                                                         \
        int4 Ia = sidx4[(kstart) >> 2];                                       \
        int4 Ib = sidx4[((kstart) + 4) >> 2];                                 \
        dst[0]  = Wc0[Ia.x * NPOST]; dst[1]  = Wc0[Ia.y * NPOST];             \
        dst[2]  = Wc0[Ia.z * NPOST]; dst[3]  = Wc0[Ia.w * NPOST];             \
        dst[4]  = Wc0[Ib.x * NPOST]; dst[5]  = Wc0[Ib.y * NPOST];             \
        dst[6]  = Wc0[Ib.z * NPOST]; dst[7]  = Wc0[Ib.w * NPOST];             \
        dst[8]  = Wc1[Ia.x * NPOST]; dst[9]  = Wc1[Ia.y * NPOST];             \
        dst[10] = Wc1[Ia.z * NPOST]; dst[11] = Wc1[Ia.w * NPOST];             \
        dst[12] = Wc1[Ib.x * NPOST]; dst[13] = Wc1[Ib.y * NPOST];             \
        dst[14] = Wc1[Ib.z * NPOST]; dst[15] = Wc1[Ib.w * NPOST];             \
    }

    float wv[2 * KPW], wn[2 * KPW];
    LOADW2(kbase, wv);

    for (int ch = 0; ch < NCHK; ++ch) {
        const int kk0 = ch * CLEN + kbase;
        // prefetch next chunk's weights (in flight across barriers)
        if (ch < NCHK - 1) LOADW2(kk0 + CLEN, wn);
        // wave-local partials over its 8 k's (tab reads are wave-uniform broadcasts)
        float a0 = 0.0f, b0 = 0.0f, a1 = 0.0f, b1 = 0.0f;
#pragma unroll
        for (int i = 0; i < KPW; ++i) {
            float4 t = tab[kk0 + i];
            a0 = fmaf(wv[i],       t.y, a0);
            b0 = fmaf(wv[i],       t.z, b0);
            a1 = fmaf(wv[KPW + i], t.y, a1);
            b1 = fmaf(wv[KPW + i], t.z, b1);
        }
        pA[wid][lane]      = a0; pB[wid][lane]      = b0;
        pA[wid][64 + lane] = a1; pB[wid][64 + lane] = b1;
        __syncthreads();

        if (wid < 2) {
            const int n = (wid << 6) + lane;
            // sub-gated prefix over the 16 wave-partials: gate every KPW k's.
            // Gate at boundary m: V(s_m) >= 1  <=>  crossing in some window k < m.
#pragma unroll
            for (int w = 0; w < NW; ++w) {
                float nA = offA + pA[w][n];
                float nB = offB + pB[w][n];
                if (!doneJ) {
                    float4 tn = tab[ch * CLEN + (w + 1) * KPW];   // last: pad ok
                    float gate = fmaf(nA, tn.x, -nB);
                    if (gate >= tn.y) {
                        baseK = ch * CLEN + w * KPW;
                        preA = offA; preB = offB;
                        doneJ = true;
                    }
                }
                offA = nA; offB = nB;
            }
            bool all = __all(doneJ);
            if (lane == 0) flags[wid] = all ? 1 : 0;
        }
        __syncthreads();
        if (flags[0] & flags[1]) break;                // uniform across block
        if (ch < NCHK - 1) {
#pragma unroll
            for (int i = 0; i < 2 * KPW; ++i) wv[i] = wn[i];
        }
    }

    // ================= resolve: waves 0-1, one neuron per lane =====================
    if (wid < 2) {
        const int n = (wid << 6) + lane;
        const float* __restrict__ Wcol = Wt + j0 + n;
        float result = INFINITY;
        const float INV_E = 0.36787944117144233f;
        if (doneJ) {
            // fine delayed-gate rescan of the 8-k group [baseK, baseK+KPW)
            float wl[KPW];
#pragma unroll
            for (int i = 0; i < KPW; ++i) wl[i] = Wcol[sidx[baseK + i] * NPOST];
            float A = preA, Bq = preB;
            int fk = -1; float fA = 0.0f, fB = 0.0f;
#pragma unroll
            for (int i = 0; i < KPW; ++i) {
                const int k = baseK + i;
                float4 t = tab[k];
                A  = fmaf(wl[i], t.y, A);
                Bq = fmaf(wl[i], t.z, Bq);
                if (fk < 0) {
                    // window k: V(s_{k+1}) >= 1, prefix inclusive of k
                    float4 tn = tab[k + 1];
                    float gate = fmaf(A, tn.x, -Bq);
                    if (gate >= tn.y) { fA = A; fB = Bq; fk = k; }
                }
            }

            if (fk >= 0) {
                float r  = fB / fA;
                float ez = expf(fminf(fmaxf(r, -30.0f), 30.0f));
                float z  = -ez / fA;
                bool valid = (fA > 0.0f) && (z >= -INV_E);
                float t = r - lambertw0_f(z);
                bool ok = valid && (t >= tab[fk].x) && (fk == NPRE - 1 || t <= tab[fk + 1].x);
                if (ok) {
                    result = t;
                } else {
                    // rare fp-edge fallback: faithful sequential scan from fk+1
                    float A2 = fA, B2 = fB;
                    for (int k = fk + 1; k < NPRE; ++k) {
                        float w = Wcol[sidx[k] * NPOST];
                        float4 t3 = tab[k];
                        A2 = fmaf(w, t3.y, A2);
                        B2 = fmaf(w, t3.z, B2);
                        if (A2 <= 0.0f) continue;
                        float r2  = B2 / A2;
                        float ez2 = expf(fminf(fmaxf(r2, -30.0f), 30.0f));
                        float z2  = -ez2 / A2;
                        if (z2 < -INV_E) continue;
                        float t2 = r2 - lambertw0_f(z2);
                        if (t2 < t3.x) continue;
                        if (k < NPRE - 1 && t2 > tab[k + 1].x) continue;
                        result = t2;
                        break;
                    }
                }
            } else {
                // ultra-rare grouping/sequential mismatch: faithful full scan from 0
                float A2 = 0.0f, B2 = 0.0f;
                for (int k = 0; k < NPRE; ++k) {
                    float w = Wcol[sidx[k] * NPOST];
                    float4 t3 = tab[k];
                    A2 = fmaf(w, t3.y, A2);
                    B2 = fmaf(w, t3.z, B2);
                    if (A2 <= 0.0f) continue;
                    float r2  = B2 / A2;
                    float ez2 = expf(fminf(fmaxf(r2, -30.0f), 30.0f));
                    float z2  = -ez2 / A2;
                    if (z2 < -INV_E) continue;
                    float t2 = r2 - lambertw0_f(z2);
                    if (t2 < t3.x) continue;
                    if (k < NPRE - 1 && t2 > tab[k + 1].x) continue;
                    result = t2;
                    break;
                }
            }
        }
        out[b * NPOST + j0 + n] = result;
    }
}

extern "C" void kernel_launch(void* const* d_in, const int* in_sizes, int n_in,
                              void* d_out, int out_size, void* d_ws, size_t ws_size,
                              hipStream_t stream) {
    const float* spikes  = (const float*)d_in[0];   // (128, 1024) f32
    const float* weights = (const float*)d_in[1];   // (1024, 256) f32
    float* outp = (float*)d_out;                    // (128, 256) f32
    ttfs_kernel<<<dim3(BATCH * 2), dim3(1024), 0, stream>>>(spikes, weights, outp);
}